// Round 1
// baseline (208.475 us; speedup 1.0000x reference)
//
#include <hip/hip_runtime.h>
#include <math.h>

typedef unsigned int uint;
typedef unsigned short ushort;
typedef __attribute__((ext_vector_type(8))) short bf16x8;
typedef __attribute__((ext_vector_type(4))) float f32x4;

static constexpr int Mdim = 4096;
static constexpr int Ndim = 4096;
static constexpr int Kdim = 4096;
static constexpr int Hdim = 4096;

// ---------------- numerics helpers ----------------

// Round f32 -> e4m3fn (OCP) value, returned as f32. RNE, handles subnormals.
// Software implementation (rintf is RNE) so behavior is bit-exact vs ml_dtypes
// for all in-range values (no overflow occurs in this problem; saturate anyway).
__device__ __forceinline__ float fp8_round(float v) {
  float a = fabsf(v);
  float q;
  if (a >= 0x1p-6f) {           // normal range: value = 1.mmm * 2^e, quantum 2^(e-3)
    uint u = __float_as_uint(a);
    int e = (int)(u >> 23) - 127;
    float quant = __uint_as_float((uint)(e - 3 + 127) << 23);
    q = rintf(a / quant) * quant;
    q = fminf(q, 448.f);
  } else {                      // subnormal: quantum 2^-9 (also rounds tiny -> 0)
    q = rintf(a * 512.f) * 0x1p-9f;
  }
  return copysignf(q, v);
}

// e2m1 round matching jnp.searchsorted(side='left'): |v|==bound maps DOWN.
// t must already be clipped to [-6,6].
__device__ __forceinline__ float e2m1_round(float t) {
  float a = fabsf(t);
  float q;
  if (a <= 0.25f) q = 0.f;
  else if (a <= 0.75f) q = 0.5f;
  else if (a <= 1.25f) q = 1.f;
  else if (a <= 1.75f) q = 1.5f;
  else if (a <= 2.5f)  q = 2.f;
  else if (a <= 3.5f)  q = 3.f;
  else if (a <= 5.f)   q = 4.f;
  else                 q = 6.f;
  return copysignf(q, t);
}

// e2m1 4-bit code -> f32 value. mag 0->0, 1->0.5, 2..7 -> (1+0.5*(m&1))*2^((m>>1)-1)
__device__ __forceinline__ float e2m1_decode(uint c) {
  uint m = c & 7u;
  float v;
  if (m == 0u) v = 0.f;
  else if (m == 1u) v = 0.5f;
  else v = __uint_as_float(((126u + (m >> 1)) << 23) | ((m & 1u) << 22));
  return (c & 8u) ? -v : v;
}

// ---------------- kernel 1: SiLU-mul + NVFP4 fake-quant -> bf16 a_deq ----------------

__global__ void silu_quant_kernel(const float* __restrict__ x, ushort* __restrict__ a_deq,
                                  const float* __restrict__ scalep) {
  const int g = blockIdx.x * 256 + threadIdx.x;   // one thread per 16-elem block
  const int row = g >> 8;
  const int blk = g & 255;
  const float gs = 1.0f / scalep[0];
  const float c6 = gs / 6.0f;
  const float* gp = x + (size_t)row * (2 * Hdim) + blk * 16;
  const float* up = gp + Hdim;
  float y[16];
  float amax = 0.f;
#pragma unroll
  for (int i = 0; i < 4; ++i) {
    float4 gv = ((const float4*)gp)[i];
    float4 uv = ((const float4*)up)[i];
    float ga[4] = {gv.x, gv.y, gv.z, gv.w};
    float ua[4] = {uv.x, uv.y, uv.z, uv.w};
#pragma unroll
    for (int j = 0; j < 4; ++j) {
      float xv = ga[j];
      float sig = 1.0f / (1.0f + expf(-xv));
      float yy = xv * sig * ua[j];
      y[i * 4 + j] = yy;
      amax = fmaxf(amax, fabsf(yy));
    }
  }
  const float sf = fp8_round(amax * c6);
  uint outp[8];
  if (sf > 0.f) {
    const float inv = gs / sf;
#pragma unroll
    for (int i = 0; i < 8; ++i) {
      float t0 = fminf(fmaxf(y[2 * i] * inv, -6.f), 6.f);
      float t1 = fminf(fmaxf(y[2 * i + 1] * inv, -6.f), 6.f);
      float d0 = e2m1_round(t0) * sf;   // exact in bf16 (<=5 sig bits)
      float d1 = e2m1_round(t1) * sf;
      outp[i] = (__float_as_uint(d0) >> 16) | ((__float_as_uint(d1) >> 16) << 16);
    }
  } else {
#pragma unroll
    for (int i = 0; i < 8; ++i) outp[i] = 0u;
  }
  uint4* dst = (uint4*)(a_deq + (size_t)row * Hdim + blk * 16);
  dst[0] = (uint4){outp[0], outp[1], outp[2], outp[3]};
  dst[1] = (uint4){outp[4], outp[5], outp[6], outp[7]};
}

// ---------------- kernel 2: weight nibble unpack + fp8-scale dequant -> bf16 b_deq ----------------

__global__ void wdeq_kernel(const int* __restrict__ w, const float* __restrict__ wscale,
                            ushort* __restrict__ b_deq) {
  const int g = blockIdx.x * 256 + threadIdx.x;   // one thread per 16-k block (8 bytes)
  const int n = g >> 8;
  const int blk = g & 255;
  const int4* wp = (const int4*)(w + (size_t)n * (Hdim / 2) + blk * 8);
  int4 w0 = wp[0], w1 = wp[1];
  int wb[8] = {w0.x, w0.y, w0.z, w0.w, w1.x, w1.y, w1.z, w1.w};
  const float ws = fp8_round(wscale[(size_t)n * (Hdim / 16) + blk]);
  uint outp[8];
#pragma unroll
  for (int i = 0; i < 8; ++i) {
    uint byte = (uint)wb[i] & 0xFFu;
    float vlo = e2m1_decode(byte & 15u) * ws;     // low nibble = even k
    float vhi = e2m1_decode(byte >> 4) * ws;      // high nibble = odd k
    outp[i] = (__float_as_uint(vlo) >> 16) | ((__float_as_uint(vhi) >> 16) << 16);
  }
  uint4* dst = (uint4*)(b_deq + (size_t)n * Hdim + blk * 16);
  dst[0] = (uint4){outp[0], outp[1], outp[2], outp[3]};
  dst[1] = (uint4){outp[4], outp[5], outp[6], outp[7]};
}

// ---------------- kernel 3: bf16 GEMM  C = alpha * A @ B^T ----------------
// m97 structure: 128x128 tile, BK=64, 4 waves (2x2), 4x4 16x16x32 fragments/wave,
// global_load_lds width 16 with pre-swizzled global source (XOR row&7 chunk swizzle).

#define BM 128
#define BN 128
#define BK 64

__device__ __forceinline__ void gload_lds16(const ushort* g, ushort* l) {
  __builtin_amdgcn_global_load_lds((const __attribute__((address_space(1))) void*)g,
                                   (__attribute__((address_space(3))) void*)l,
                                   16, 0, 0);
}

__global__ __launch_bounds__(256) void gemm_bt(const ushort* __restrict__ A,
                                               const ushort* __restrict__ B,
                                               float* __restrict__ C,
                                               const float* __restrict__ scalep,
                                               const float* __restrict__ wscale2p) {
  __shared__ alignas(16) ushort As[BM * BK];   // 16 KB, rows of 64 bf16 (128 B)
  __shared__ alignas(16) ushort Bs[BN * BK];   // 16 KB
  const int tid = threadIdx.x;
  const int wave = tid >> 6;
  const int lane = tid & 63;
  const int wr = wave >> 1;        // wave row (0..1) -> 64 rows of C
  const int wc = wave & 1;         // wave col (0..1) -> 64 cols of C
  const int m0 = blockIdx.y * BM;
  const int n0 = blockIdx.x * BN;
  const int fr = lane & 15;        // fragment row index
  const int fq = lane >> 4;        // k-group / C row group

  f32x4 acc[4][4];
#pragma unroll
  for (int i = 0; i < 4; ++i)
#pragma unroll
    for (int j = 0; j < 4; ++j) acc[i][j] = (f32x4){0.f, 0.f, 0.f, 0.f};

  const int srow = lane >> 3;      // row within 8-row staging chunk
  const int scol = lane & 7;       // 16B chunk position within row

  for (int k0 = 0; k0 < Kdim; k0 += BK) {
    // stage A,B tiles: per wave 4+4 global_load_lds (1 KB each). LDS dest linear;
    // source chunk pre-swizzled so LDS content is XOR-swizzled (T2-style).
#pragma unroll
    for (int i = 0; i < 4; ++i) {
      const int c = i * 4 + wave;            // 1KB chunk id 0..15
      const int row = c * 8 + srow;          // tile row 0..127
      const int sc = scol ^ (row & 7);       // pre-swizzled source chunk
      gload_lds16(A + (size_t)(m0 + row) * Kdim + k0 + sc * 8, &As[c * 512]);
      gload_lds16(B + (size_t)(n0 + row) * Kdim + k0 + sc * 8, &Bs[c * 512]);
    }
    __syncthreads();
#pragma unroll
    for (int kk = 0; kk < 2; ++kk) {
      bf16x8 af[4], bfr[4];
#pragma unroll
      for (int mi = 0; mi < 4; ++mi) {
        const int r = wr * 64 + mi * 16 + fr;
        const int ck = (kk * 4 + fq) ^ (r & 7);          // swizzled read
        af[mi] = *(const bf16x8*)(As + r * 64 + ck * 8);
      }
#pragma unroll
      for (int ni = 0; ni < 4; ++ni) {
        const int r = wc * 64 + ni * 16 + fr;
        const int ck = (kk * 4 + fq) ^ (r & 7);
        bfr[ni] = *(const bf16x8*)(Bs + r * 64 + ck * 8);
      }
#pragma unroll
      for (int mi = 0; mi < 4; ++mi)
#pragma unroll
        for (int ni = 0; ni < 4; ++ni)
          acc[mi][ni] = __builtin_amdgcn_mfma_f32_16x16x32_bf16(af[mi], bfr[ni],
                                                                acc[mi][ni], 0, 0, 0);
    }
    __syncthreads();
  }

  const float alpha = scalep[0] * wscale2p[0];
#pragma unroll
  for (int mi = 0; mi < 4; ++mi)
#pragma unroll
    for (int ni = 0; ni < 4; ++ni) {
      const int col = n0 + wc * 64 + ni * 16 + fr;
      const int rbase = m0 + wr * 64 + mi * 16 + fq * 4;
#pragma unroll
      for (int r = 0; r < 4; ++r)
        C[(size_t)(rbase + r) * Ndim + col] = alpha * acc[mi][ni][r];
    }
}

// ---------------- launcher ----------------

extern "C" void kernel_launch(void* const* d_in, const int* in_sizes, int n_in,
                              void* d_out, int out_size, void* d_ws, size_t ws_size,
                              hipStream_t stream) {
  const float* x       = (const float*)d_in[0];
  const int*   w       = (const int*)d_in[1];
  const float* wscale  = (const float*)d_in[2];
  const float* wscale2 = (const float*)d_in[3];
  const float* scale   = (const float*)d_in[4];
  float* out = (float*)d_out;

  ushort* a_deq = (ushort*)d_ws;                       // 32 MB
  ushort* b_deq = a_deq + (size_t)Mdim * Kdim;         // 32 MB

  silu_quant_kernel<<<Mdim, 256, 0, stream>>>(x, a_deq, scale);
  wdeq_kernel<<<Ndim, 256, 0, stream>>>(w, wscale, b_deq);
  gemm_bt<<<dim3(Ndim / BN, Mdim / BM), 256, 0, stream>>>(a_deq, b_deq, out, scale, wscale2);
}

// Round 2
// 166.773 us; speedup vs baseline: 1.2501x; 1.2501x over previous
//
#include <hip/hip_runtime.h>
#include <math.h>

typedef unsigned int uint;
typedef unsigned short ushort;
typedef __attribute__((ext_vector_type(8))) short bf16x8;
typedef __attribute__((ext_vector_type(4))) float f32x4;

static constexpr int Mdim = 4096;
static constexpr int Ndim = 4096;
static constexpr int Kdim = 4096;
static constexpr int Hdim = 4096;

// ---------------- numerics helpers ----------------

__device__ __forceinline__ float fp8_round(float v) {
  float a = fabsf(v);
  float q;
  if (a >= 0x1p-6f) {           // normal range: quantum 2^(e-3)
    uint u = __float_as_uint(a);
    int e = (int)(u >> 23) - 127;
    float quant = __uint_as_float((uint)(e - 3 + 127) << 23);
    q = rintf(a / quant) * quant;
    q = fminf(q, 448.f);
  } else {                      // subnormal: quantum 2^-9
    q = rintf(a * 512.f) * 0x1p-9f;
  }
  return copysignf(q, v);
}

__device__ __forceinline__ float e2m1_round(float t) {
  float a = fabsf(t);
  float q;
  if (a <= 0.25f) q = 0.f;
  else if (a <= 0.75f) q = 0.5f;
  else if (a <= 1.25f) q = 1.f;
  else if (a <= 1.75f) q = 1.5f;
  else if (a <= 2.5f)  q = 2.f;
  else if (a <= 3.5f)  q = 3.f;
  else if (a <= 5.f)   q = 4.f;
  else                 q = 6.f;
  return copysignf(q, t);
}

__device__ __forceinline__ float e2m1_decode(uint c) {
  uint m = c & 7u;
  float v;
  if (m == 0u) v = 0.f;
  else if (m == 1u) v = 0.5f;
  else v = __uint_as_float(((126u + (m >> 1)) << 23) | ((m & 1u) << 22));
  return (c & 8u) ? -v : v;
}

// ---------------- kernel 1: SiLU-mul + NVFP4 fake-quant -> bf16 a_deq ----------------

__global__ void silu_quant_kernel(const float* __restrict__ x, ushort* __restrict__ a_deq,
                                  const float* __restrict__ scalep) {
  const int g = blockIdx.x * 256 + threadIdx.x;
  const int row = g >> 8;
  const int blk = g & 255;
  const float gs = 1.0f / scalep[0];
  const float c6 = gs / 6.0f;
  const float* gp = x + (size_t)row * (2 * Hdim) + blk * 16;
  const float* up = gp + Hdim;
  float y[16];
  float amax = 0.f;
#pragma unroll
  for (int i = 0; i < 4; ++i) {
    float4 gv = ((const float4*)gp)[i];
    float4 uv = ((const float4*)up)[i];
    float ga[4] = {gv.x, gv.y, gv.z, gv.w};
    float ua[4] = {uv.x, uv.y, uv.z, uv.w};
#pragma unroll
    for (int j = 0; j < 4; ++j) {
      float xv = ga[j];
      float sig = 1.0f / (1.0f + expf(-xv));
      float yy = xv * sig * ua[j];
      y[i * 4 + j] = yy;
      amax = fmaxf(amax, fabsf(yy));
    }
  }
  const float sf = fp8_round(amax * c6);
  uint outp[8];
  if (sf > 0.f) {
    const float inv = gs / sf;
#pragma unroll
    for (int i = 0; i < 8; ++i) {
      float t0 = fminf(fmaxf(y[2 * i] * inv, -6.f), 6.f);
      float t1 = fminf(fmaxf(y[2 * i + 1] * inv, -6.f), 6.f);
      float d0 = e2m1_round(t0) * sf;
      float d1 = e2m1_round(t1) * sf;
      outp[i] = (__float_as_uint(d0) >> 16) | ((__float_as_uint(d1) >> 16) << 16);
    }
  } else {
#pragma unroll
    for (int i = 0; i < 8; ++i) outp[i] = 0u;
  }
  uint4* dst = (uint4*)(a_deq + (size_t)row * Hdim + blk * 16);
  dst[0] = (uint4){outp[0], outp[1], outp[2], outp[3]};
  dst[1] = (uint4){outp[4], outp[5], outp[6], outp[7]};
}

// ---------------- kernel 2: weight dequant -> bf16 b_deq ----------------

__global__ void wdeq_kernel(const int* __restrict__ w, const float* __restrict__ wscale,
                            ushort* __restrict__ b_deq) {
  const int g = blockIdx.x * 256 + threadIdx.x;
  const int n = g >> 8;
  const int blk = g & 255;
  const int4* wp = (const int4*)(w + (size_t)n * (Hdim / 2) + blk * 8);
  int4 w0 = wp[0], w1 = wp[1];
  int wb[8] = {w0.x, w0.y, w0.z, w0.w, w1.x, w1.y, w1.z, w1.w};
  const float ws = fp8_round(wscale[(size_t)n * (Hdim / 16) + blk]);
  uint outp[8];
#pragma unroll
  for (int i = 0; i < 8; ++i) {
    uint byte = (uint)wb[i] & 0xFFu;
    float vlo = e2m1_decode(byte & 15u) * ws;
    float vhi = e2m1_decode(byte >> 4) * ws;
    outp[i] = (__float_as_uint(vlo) >> 16) | ((__float_as_uint(vhi) >> 16) << 16);
  }
  uint4* dst = (uint4*)(b_deq + (size_t)n * Hdim + blk * 16);
  dst[0] = (uint4){outp[0], outp[1], outp[2], outp[3]};
  dst[1] = (uint4){outp[4], outp[5], outp[6], outp[7]};
}

// ---------------- kernel 3: 256x256 8-phase bf16 GEMM  C = alpha * A @ B^T ----------------
// 8 waves (2M x 4N), BK=64, 2-slot LDS double buffer (128 KiB), 4 quadrant-phases
// per K-tile, 1 half-tile staged per phase via global_load_lds dwordx4, counted
// vmcnt(4) once per K-tile. B-frags register-resident after phase 0 -> B region
// retires early, enabling B(kt+2) staging into the CURRENT slot at phases 2-3.
// Pipeline ledger (issue -> landed-by):
//   A(kt+1): issued kt.ph0/ph1 -> vmcnt(4) at kt.ph3 forces landing (4 newest = B(kt+2)).
//   B(kt+2): issued kt.ph2/ph3 -> forced landed by vmcnt(4) at (kt+1).ph3.
// Write-safety: A-slot overwritten only after previous occupant's last ds_read
// (barrier-ordered at previous K-tile ph3); B region after its only reads (ph0).

#define BM 256
#define BN 256
#define BK 64
#define NT (Kdim / BK)
#define TILE_E (256 * 64)     // elements per A- or B-tile (32 KB)
#define SLOT_E (2 * TILE_E)

__device__ __forceinline__ void gload_lds16(const ushort* g, ushort* l) {
  __builtin_amdgcn_global_load_lds((const __attribute__((address_space(1))) void*)g,
                                   (__attribute__((address_space(3))) void*)l,
                                   16, 0, 0);
}

// Stage one half-tile (128 rows x 64 cols bf16, 16 KB) = 2 rounds x 1 load/thread.
// LDS dest linear per wave (wave-uniform base + lane*16B); global source chunk
// pre-swizzled (c ^ (row&7)) so LDS holds the XOR-swizzled layout.
__device__ __forceinline__ void stage_half(ushort* tile, const ushort* mat, int gbase,
                                           int half, int kcol, int wave, int lane) {
#pragma unroll
  for (int rr = 0; rr < 2; ++rr) {
    const int rowbase = half * 128 + rr * 64 + wave * 8;   // wave-uniform
    const int trow = rowbase + (lane >> 3);
    const int sc = (lane & 7) ^ (trow & 7);
    gload_lds16(mat + (size_t)(gbase + trow) * Kdim + kcol + sc * 8, tile + rowbase * 64);
  }
}

__device__ __forceinline__ bf16x8 lds_frag(const ushort* tile, int r, int ck) {
  return *(const bf16x8*)(tile + r * 64 + ((ck ^ (r & 7)) * 8));
}

__global__ __launch_bounds__(512, 2) void gemm256(const ushort* __restrict__ A,
                                                  const ushort* __restrict__ B,
                                                  float* __restrict__ C,
                                                  const float* __restrict__ scalep,
                                                  const float* __restrict__ wscale2p) {
  extern __shared__ __align__(16) ushort lds[];   // 131072 B
  const int tid = threadIdx.x;
  const int wave = tid >> 6;
  const int lane = tid & 63;
  const int wm = wave >> 2;        // 0..1 -> 128 C-rows
  const int wn = wave & 3;         // 0..3 -> 64 C-cols
  const int fr = lane & 15;
  const int fq = lane >> 4;

  // XCD-aware swizzle: 256 blocks, 256%8==0 -> simple variant is bijective
  const int wg = blockIdx.x;
  const int swz = (wg & 7) * 32 + (wg >> 3);
  const int m0 = (swz >> 4) * BM;
  const int n0 = (swz & 15) * BN;

  f32x4 acc[8][4];
#pragma unroll
  for (int i = 0; i < 8; ++i)
#pragma unroll
    for (int j = 0; j < 4; ++j) acc[i][j] = (f32x4){0.f, 0.f, 0.f, 0.f};

  ushort* slot0 = lds;
  ushort* slot1 = lds + SLOT_E;

  // prologue: K-tile 0 (A+B) + B of K-tile 1  (12 loads/thread)
  stage_half(slot0, A, m0, 0, 0, wave, lane);
  stage_half(slot0, A, m0, 1, 0, wave, lane);
  stage_half(slot0 + TILE_E, B, n0, 0, 0, wave, lane);
  stage_half(slot0 + TILE_E, B, n0, 1, 0, wave, lane);
  stage_half(slot1 + TILE_E, B, n0, 0, BK, wave, lane);
  stage_half(slot1 + TILE_E, B, n0, 1, BK, wave, lane);
  asm volatile("s_waitcnt vmcnt(4)" ::: "memory");   // K-tile 0 landed; B(1) in flight
  __builtin_amdgcn_s_barrier();

  for (int kt = 0; kt < NT; ++kt) {
    const int cur = kt & 1;
    ushort* Acur = lds + cur * SLOT_E;
    ushort* Bcur = Acur + TILE_E;
    ushort* Anext = lds + (cur ^ 1) * SLOT_E;
    const int kA = (kt + 1) * BK;
    const int kB = (kt + 2) * BK;
    const bool haveA = (kt + 1 < NT);
    const bool haveB = (kt + 2 < NT);

    bf16x8 bfr[4][2];

    // ---------------- phase 0: B-frags + A quadrant 0; stage A(kt+1) half0 ----------------
    {
#pragma unroll
      for (int ni = 0; ni < 4; ++ni)
#pragma unroll
        for (int kk = 0; kk < 2; ++kk)
          bfr[ni][kk] = lds_frag(Bcur, wn * 64 + ni * 16 + fr, kk * 4 + fq);
      bf16x8 af[2][2];
#pragma unroll
      for (int m2 = 0; m2 < 2; ++m2)
#pragma unroll
        for (int kk = 0; kk < 2; ++kk)
          af[m2][kk] = lds_frag(Acur, wm * 128 + m2 * 16 + fr, kk * 4 + fq);
      asm volatile("" ::: "memory");
      if (haveA) stage_half(Anext, A, m0, 0, kA, wave, lane);
      __builtin_amdgcn_s_barrier();
      asm volatile("s_waitcnt lgkmcnt(0)" ::: "memory");
      __builtin_amdgcn_s_setprio(1);
#pragma unroll
      for (int m2 = 0; m2 < 2; ++m2)
#pragma unroll
        for (int ni = 0; ni < 4; ++ni)
#pragma unroll
          for (int kk = 0; kk < 2; ++kk)
            acc[m2][ni] = __builtin_amdgcn_mfma_f32_16x16x32_bf16(af[m2][kk], bfr[ni][kk],
                                                                  acc[m2][ni], 0, 0, 0);
      __builtin_amdgcn_s_setprio(0);
      __builtin_amdgcn_s_barrier();
    }
    // ---------------- phase 1: A quadrant 1; stage A(kt+1) half1 ----------------
    {
      bf16x8 af[2][2];
#pragma unroll
      for (int m2 = 0; m2 < 2; ++m2)
#pragma unroll
        for (int kk = 0; kk < 2; ++kk)
          af[m2][kk] = lds_frag(Acur, wm * 128 + (2 + m2) * 16 + fr, kk * 4 + fq);
      asm volatile("" ::: "memory");
      if (haveA) stage_half(Anext, A, m0, 1, kA, wave, lane);
      __builtin_amdgcn_s_barrier();
      asm volatile("s_waitcnt lgkmcnt(0)" ::: "memory");
      __builtin_amdgcn_s_setprio(1);
#pragma unroll
      for (int m2 = 0; m2 < 2; ++m2)
#pragma unroll
        for (int ni = 0; ni < 4; ++ni)
#pragma unroll
          for (int kk = 0; kk < 2; ++kk)
            acc[2 + m2][ni] = __builtin_amdgcn_mfma_f32_16x16x32_bf16(af[m2][kk], bfr[ni][kk],
                                                                      acc[2 + m2][ni], 0, 0, 0);
      __builtin_amdgcn_s_setprio(0);
      __builtin_amdgcn_s_barrier();
    }
    // ---------------- phase 2: A quadrant 2; stage B(kt+2) half0 into Bcur ----------------
    {
      bf16x8 af[2][2];
#pragma unroll
      for (int m2 = 0; m2 < 2; ++m2)
#pragma unroll
        for (int kk = 0; kk < 2; ++kk)
          af[m2][kk] = lds_frag(Acur, wm * 128 + (4 + m2) * 16 + fr, kk * 4 + fq);
      asm volatile("" ::: "memory");
      if (haveB) stage_half(Bcur, B, n0, 0, kB, wave, lane);
      __builtin_amdgcn_s_barrier();
      asm volatile("s_waitcnt lgkmcnt(0)" ::: "memory");
      __builtin_amdgcn_s_setprio(1);
#pragma unroll
      for (int m2 = 0; m2 < 2; ++m2)
#pragma unroll
        for (int ni = 0; ni < 4; ++ni)
#pragma unroll
          for (int kk = 0; kk < 2; ++kk)
            acc[4 + m2][ni] = __builtin_amdgcn_mfma_f32_16x16x32_bf16(af[m2][kk], bfr[ni][kk],
                                                                      acc[4 + m2][ni], 0, 0, 0);
      __builtin_amdgcn_s_setprio(0);
      __builtin_amdgcn_s_barrier();
    }
    // ---------------- phase 3: A quadrant 3; stage B(kt+2) half1; vmcnt checkpoint ----------------
    {
      bf16x8 af[2][2];
#pragma unroll
      for (int m2 = 0; m2 < 2; ++m2)
#pragma unroll
        for (int kk = 0; kk < 2; ++kk)
          af[m2][kk] = lds_frag(Acur, wm * 128 + (6 + m2) * 16 + fr, kk * 4 + fq);
      asm volatile("" ::: "memory");
      if (haveB) stage_half(Bcur, B, n0, 1, kB, wave, lane);
      __builtin_amdgcn_s_barrier();
      asm volatile("s_waitcnt lgkmcnt(0)" ::: "memory");
      __builtin_amdgcn_s_setprio(1);
#pragma unroll
      for (int m2 = 0; m2 < 2; ++m2)
#pragma unroll
        for (int ni = 0; ni < 4; ++ni)
#pragma unroll
          for (int kk = 0; kk < 2; ++kk)
            acc[6 + m2][ni] = __builtin_amdgcn_mfma_f32_16x16x32_bf16(af[m2][kk], bfr[ni][kk],
                                                                      acc[6 + m2][ni], 0, 0, 0);
      __builtin_amdgcn_s_setprio(0);
      if (haveB) asm volatile("s_waitcnt vmcnt(4)" ::: "memory");   // keep B(kt+2) in flight
      else       asm volatile("s_waitcnt vmcnt(0)" ::: "memory");   // tail: drain
      __builtin_amdgcn_s_barrier();
    }
  }

  const float alpha = scalep[0] * wscale2p[0];
#pragma unroll
  for (int mi = 0; mi < 8; ++mi)
#pragma unroll
    for (int ni = 0; ni < 4; ++ni) {
      const int col = n0 + wn * 64 + ni * 16 + fr;
      const int rbase = m0 + wm * 128 + mi * 16 + fq * 4;
#pragma unroll
      for (int r = 0; r < 4; ++r)
        C[(size_t)(rbase + r) * Ndim + col] = alpha * acc[mi][ni][r];
    }
}

// ---------------- launcher ----------------

extern "C" void kernel_launch(void* const* d_in, const int* in_sizes, int n_in,
                              void* d_out, int out_size, void* d_ws, size_t ws_size,
                              hipStream_t stream) {
  const float* x       = (const float*)d_in[0];
  const int*   w       = (const int*)d_in[1];
  const float* wscale  = (const float*)d_in[2];
  const float* wscale2 = (const float*)d_in[3];
  const float* scale   = (const float*)d_in[4];
  float* out = (float*)d_out;

  ushort* a_deq = (ushort*)d_ws;                       // 32 MB
  ushort* b_deq = a_deq + (size_t)Mdim * Kdim;         // 32 MB

  silu_quant_kernel<<<Mdim, 256, 0, stream>>>(x, a_deq, scale);
  wdeq_kernel<<<Ndim, 256, 0, stream>>>(w, wscale, b_deq);

  hipFuncSetAttribute((const void*)gemm256, hipFuncAttributeMaxDynamicSharedMemorySize, 131072);
  gemm256<<<(Mdim / BM) * (Ndim / BN), 512, 131072, stream>>>(a_deq, b_deq, out, scale, wscale2);
}

// Round 3
// 164.442 us; speedup vs baseline: 1.2678x; 1.0142x over previous
//
#include <hip/hip_runtime.h>
#include <math.h>

typedef unsigned int uint;
typedef unsigned short ushort;
typedef __attribute__((ext_vector_type(8))) short bf16x8;
typedef __attribute__((ext_vector_type(4))) float f32x4;

static constexpr int Mdim = 4096;
static constexpr int Ndim = 4096;
static constexpr int Kdim = 4096;
static constexpr int Hdim = 4096;

// ---------------- numerics helpers ----------------

__device__ __forceinline__ float fp8_round(float v) {
  float a = fabsf(v);
  float q;
  if (a >= 0x1p-6f) {           // normal range: quantum 2^(e-3)
    uint u = __float_as_uint(a);
    int e = (int)(u >> 23) - 127;
    float quant = __uint_as_float((uint)(e - 3 + 127) << 23);
    q = rintf(a / quant) * quant;
    q = fminf(q, 448.f);
  } else {                      // subnormal: quantum 2^-9
    q = rintf(a * 512.f) * 0x1p-9f;
  }
  return copysignf(q, v);
}

__device__ __forceinline__ float e2m1_round(float t) {
  float a = fabsf(t);
  float q;
  if (a <= 0.25f) q = 0.f;
  else if (a <= 0.75f) q = 0.5f;
  else if (a <= 1.25f) q = 1.f;
  else if (a <= 1.75f) q = 1.5f;
  else if (a <= 2.5f)  q = 2.f;
  else if (a <= 3.5f)  q = 3.f;
  else if (a <= 5.f)   q = 4.f;
  else                 q = 6.f;
  return copysignf(q, t);
}

__device__ __forceinline__ float e2m1_decode(uint c) {
  uint m = c & 7u;
  float v;
  if (m == 0u) v = 0.f;
  else if (m == 1u) v = 0.5f;
  else v = __uint_as_float(((126u + (m >> 1)) << 23) | ((m & 1u) << 22));
  return (c & 8u) ? -v : v;
}

// ---------------- kernel 1: SiLU-mul + NVFP4 fake-quant -> bf16 a_deq ----------------

__global__ void silu_quant_kernel(const float* __restrict__ x, ushort* __restrict__ a_deq,
                                  const float* __restrict__ scalep) {
  const int g = blockIdx.x * 256 + threadIdx.x;
  const int row = g >> 8;
  const int blk = g & 255;
  const float gs = 1.0f / scalep[0];
  const float c6 = gs / 6.0f;
  const float* gp = x + (size_t)row * (2 * Hdim) + blk * 16;
  const float* up = gp + Hdim;
  float y[16];
  float amax = 0.f;
#pragma unroll
  for (int i = 0; i < 4; ++i) {
    float4 gv = ((const float4*)gp)[i];
    float4 uv = ((const float4*)up)[i];
    float ga[4] = {gv.x, gv.y, gv.z, gv.w};
    float ua[4] = {uv.x, uv.y, uv.z, uv.w};
#pragma unroll
    for (int j = 0; j < 4; ++j) {
      float xv = ga[j];
      float sig = 1.0f / (1.0f + expf(-xv));
      float yy = xv * sig * ua[j];
      y[i * 4 + j] = yy;
      amax = fmaxf(amax, fabsf(yy));
    }
  }
  const float sf = fp8_round(amax * c6);
  uint outp[8];
  if (sf > 0.f) {
    const float inv = gs / sf;
#pragma unroll
    for (int i = 0; i < 8; ++i) {
      float t0 = fminf(fmaxf(y[2 * i] * inv, -6.f), 6.f);
      float t1 = fminf(fmaxf(y[2 * i + 1] * inv, -6.f), 6.f);
      float d0 = e2m1_round(t0) * sf;
      float d1 = e2m1_round(t1) * sf;
      outp[i] = (__float_as_uint(d0) >> 16) | ((__float_as_uint(d1) >> 16) << 16);
    }
  } else {
#pragma unroll
    for (int i = 0; i < 8; ++i) outp[i] = 0u;
  }
  uint4* dst = (uint4*)(a_deq + (size_t)row * Hdim + blk * 16);
  dst[0] = (uint4){outp[0], outp[1], outp[2], outp[3]};
  dst[1] = (uint4){outp[4], outp[5], outp[6], outp[7]};
}

// ---------------- kernel 2: weight dequant -> bf16 b_deq ----------------

__global__ void wdeq_kernel(const int* __restrict__ w, const float* __restrict__ wscale,
                            ushort* __restrict__ b_deq) {
  const int g = blockIdx.x * 256 + threadIdx.x;
  const int n = g >> 8;
  const int blk = g & 255;
  const int4* wp = (const int4*)(w + (size_t)n * (Hdim / 2) + blk * 8);
  int4 w0 = wp[0], w1 = wp[1];
  int wb[8] = {w0.x, w0.y, w0.z, w0.w, w1.x, w1.y, w1.z, w1.w};
  const float ws = fp8_round(wscale[(size_t)n * (Hdim / 16) + blk]);
  uint outp[8];
#pragma unroll
  for (int i = 0; i < 8; ++i) {
    uint byte = (uint)wb[i] & 0xFFu;
    float vlo = e2m1_decode(byte & 15u) * ws;
    float vhi = e2m1_decode(byte >> 4) * ws;
    outp[i] = (__float_as_uint(vlo) >> 16) | ((__float_as_uint(vhi) >> 16) << 16);
  }
  uint4* dst = (uint4*)(b_deq + (size_t)n * Hdim + blk * 16);
  dst[0] = (uint4){outp[0], outp[1], outp[2], outp[3]};
  dst[1] = (uint4){outp[4], outp[5], outp[6], outp[7]};
}

// ---------------- kernel 3: 256x256 bf16 GEMM, pipelined ds_reads + triple-buffered A ----------------
// 8 waves (2M x 4N), BK=64. LDS 160 KB: A x3 (96 KB) + B x2 (64 KB).
// Phase p issues phase p+1's A-frag ds_reads BEFORE its MFMA burst (DS pipe fills
// while matrix pipe executes). Stages: A(kt+2)h0@ph0, h1@ph1, B(kt+2)h0@ph2, h1@ph3.
// Checkpoint vmcnt(6) at end of ph2 (= kt's own 6 outstanding loads) forces tile
// kt+1 landed a FULL K-tile after issue; ph2's closing barrier gives cross-wave
// visibility before ph3 issues next-tile frag reads.

#define BM 256
#define BN 256
#define BK 64
#define NT (Kdim / BK)
#define TILE_E (256 * 64)     // 16384 ushort = 32 KB

__device__ __forceinline__ void gload_lds16(const ushort* g, ushort* l) {
  __builtin_amdgcn_global_load_lds((const __attribute__((address_space(1))) void*)g,
                                   (__attribute__((address_space(3))) void*)l,
                                   16, 0, 0);
}

#define BAR()                                   \
  do {                                          \
    asm volatile("" ::: "memory");              \
    __builtin_amdgcn_s_barrier();               \
    asm volatile("" ::: "memory");              \
  } while (0)

__global__ __launch_bounds__(512, 2) void gemm256(const ushort* __restrict__ A,
                                                  const ushort* __restrict__ B,
                                                  float* __restrict__ C,
                                                  const float* __restrict__ scalep,
                                                  const float* __restrict__ wscale2p) {
  extern __shared__ __align__(16) ushort lds[];   // 163840 B
  const int tid = threadIdx.x;
  const int wave = tid >> 6;
  const int lane = tid & 63;
  const int wm = wave >> 2;
  const int wn = wave & 3;
  const int fr = lane & 15;
  const int fq = lane >> 4;

  const int wg = blockIdx.x;
  const int swz = (wg & 7) * 32 + (wg >> 3);      // 256 % 8 == 0 -> bijective
  const int m0 = (swz >> 4) * BM;
  const int n0 = (swz & 15) * BN;

  f32x4 acc[8][4];
#pragma unroll
  for (int i = 0; i < 8; ++i)
#pragma unroll
    for (int j = 0; j < 4; ++j) acc[i][j] = (f32x4){0.f, 0.f, 0.f, 0.f};

  // rotating LDS slot pointers
  const ushort* pA0c;  // read: tile kt
  const ushort* pA1c;  // tile kt+1
  ushort* pA0 = lds;                  // slot 0
  ushort* pA1 = lds + TILE_E;         // slot 1
  ushort* pA2 = lds + 2 * TILE_E;     // slot 2 (stage target)
  ushort* pB0 = lds + 3 * TILE_E;     // B read slot (tile kt)
  ushort* pB1 = lds + 4 * TILE_E;     // B other (tile kt+1)

  // staging per-thread geometry (invariant): row = h*128 + rr*64 + wave*8 + lane/8
  int goffA[4], goffB[4], loff[4];
#pragma unroll
  for (int h = 0; h < 2; ++h)
#pragma unroll
    for (int rr = 0; rr < 2; ++rr) {
      const int idx = h * 2 + rr;
      const int rowb = h * 128 + rr * 64 + wave * 8;
      const int trow = rowb + (lane >> 3);
      const int sc = (lane & 7) ^ (trow & 7);
      goffA[idx] = (m0 + trow) * Kdim + sc * 8;
      goffB[idx] = (n0 + trow) * Kdim + sc * 8;
      loff[idx] = rowb * 64;
    }

#define STAGE_A(h, kcol)                                                  \
  do {                                                                    \
    gload_lds16(A + (size_t)goffA[(h)*2 + 0] + (kcol), pA2 + loff[(h)*2 + 0]); \
    gload_lds16(A + (size_t)goffA[(h)*2 + 1] + (kcol), pA2 + loff[(h)*2 + 1]); \
  } while (0)
#define STAGE_B(h, kcol)                                                  \
  do {                                                                    \
    gload_lds16(B + (size_t)goffB[(h)*2 + 0] + (kcol), pB0 + loff[(h)*2 + 0]); \
    gload_lds16(B + (size_t)goffB[(h)*2 + 1] + (kcol), pB0 + loff[(h)*2 + 1]); \
  } while (0)

  // fragment read geometry: offset(r, ck) = r*64 els + ((ck ^ (r&7))*8) els; r&7 == fr&7
  const int laneAOff = (wm * 128 + fr) * 64;
  const int laneBOff = (wn * 64 + fr) * 64;
  const int xo0 = (fq ^ (fr & 7)) * 8;            // kk = 0
  const int xo1 = ((4 + fq) ^ (fr & 7)) * 8;      // kk = 1

  // ---- prologue: stage A0,B0,A1,B1; force A0,B0; preload bfr + af0 ----
  {
    ushort* sv = pA2;
    pA2 = pA0; STAGE_A(0, 0); STAGE_A(1, 0);            // A tile0 -> slot0
    pB0 = pB0; STAGE_B(0, 0); STAGE_B(1, 0);            // B tile0 -> Bslot0
    pA2 = pA1; STAGE_A(0, BK); STAGE_A(1, BK);          // A tile1 -> slot1
    { ushort* t = pB0; pB0 = pB1; STAGE_B(0, BK); STAGE_B(1, BK); pB0 = t; }  // B tile1 -> Bslot1
    pA2 = sv;
  }
  asm volatile("s_waitcnt vmcnt(8)" ::: "memory");   // tile0 landed; tile1 in flight
  BAR();

  bf16x8 af0[2][2], bfr[4][2];
  {
    const ushort* aR0 = pA0 + laneAOff + xo0;
    const ushort* aR1 = pA0 + laneAOff + xo1;
    const ushort* bR0 = pB0 + laneBOff + xo0;
    const ushort* bR1 = pB0 + laneBOff + xo1;
#pragma unroll
    for (int ni = 0; ni < 4; ++ni) {
      bfr[ni][0] = *(const bf16x8*)(bR0 + ni * 1024);
      bfr[ni][1] = *(const bf16x8*)(bR1 + ni * 1024);
    }
#pragma unroll
    for (int m2 = 0; m2 < 2; ++m2) {
      af0[m2][0] = *(const bf16x8*)(aR0 + m2 * 1024);
      af0[m2][1] = *(const bf16x8*)(aR1 + m2 * 1024);
    }
  }

  for (int kt = 0; kt < NT; ++kt) {
    const int kc = (kt + 2) * BK;
    const bool stg = (kt + 2) < NT;
    const bool nxt = (kt + 1) < NT;
    const ushort* aR0 = pA0 + laneAOff + xo0;
    const ushort* aR1 = pA0 + laneAOff + xo1;
    bf16x8 af1[2][2], af2[2][2], af3[2][2];

    // ---- ph0: read af1; stage A(kt+2)h0; MFMA rows 0-1 ----
#pragma unroll
    for (int m2 = 0; m2 < 2; ++m2) {
      af1[m2][0] = *(const bf16x8*)(aR0 + (2 + m2) * 1024);
      af1[m2][1] = *(const bf16x8*)(aR1 + (2 + m2) * 1024);
    }
    if (stg) STAGE_A(0, kc);
    BAR();
    __builtin_amdgcn_s_setprio(1);
#pragma unroll
    for (int m2 = 0; m2 < 2; ++m2)
#pragma unroll
      for (int ni = 0; ni < 4; ++ni)
#pragma unroll
        for (int kk = 0; kk < 2; ++kk)
          acc[m2][ni] = __builtin_amdgcn_mfma_f32_16x16x32_bf16(af0[m2][kk], bfr[ni][kk],
                                                                acc[m2][ni], 0, 0, 0);
    __builtin_amdgcn_s_setprio(0);
    BAR();

    // ---- ph1: read af2; stage A(kt+2)h1; MFMA rows 2-3 ----
#pragma unroll
    for (int m2 = 0; m2 < 2; ++m2) {
      af2[m2][0] = *(const bf16x8*)(aR0 + (4 + m2) * 1024);
      af2[m2][1] = *(const bf16x8*)(aR1 + (4 + m2) * 1024);
    }
    if (stg) STAGE_A(1, kc);
    BAR();
    __builtin_amdgcn_s_setprio(1);
#pragma unroll
    for (int m2 = 0; m2 < 2; ++m2)
#pragma unroll
      for (int ni = 0; ni < 4; ++ni)
#pragma unroll
        for (int kk = 0; kk < 2; ++kk)
          acc[2 + m2][ni] = __builtin_amdgcn_mfma_f32_16x16x32_bf16(af1[m2][kk], bfr[ni][kk],
                                                                    acc[2 + m2][ni], 0, 0, 0);
    __builtin_amdgcn_s_setprio(0);
    BAR();

    // ---- ph2: read af3; stage B(kt+2)h0; MFMA rows 4-5; vmcnt checkpoint ----
#pragma unroll
    for (int m2 = 0; m2 < 2; ++m2) {
      af3[m2][0] = *(const bf16x8*)(aR0 + (6 + m2) * 1024);
      af3[m2][1] = *(const bf16x8*)(aR1 + (6 + m2) * 1024);
    }
    if (stg) STAGE_B(0, kc);
    BAR();
    __builtin_amdgcn_s_setprio(1);
#pragma unroll
    for (int m2 = 0; m2 < 2; ++m2)
#pragma unroll
      for (int ni = 0; ni < 4; ++ni)
#pragma unroll
        for (int kk = 0; kk < 2; ++kk)
          acc[4 + m2][ni] = __builtin_amdgcn_mfma_f32_16x16x32_bf16(af2[m2][kk], bfr[ni][kk],
                                                                    acc[4 + m2][ni], 0, 0, 0);
    __builtin_amdgcn_s_setprio(0);
    if (stg) asm volatile("s_waitcnt vmcnt(6)" ::: "memory");  // forces tile kt+1 landed
    else     asm volatile("s_waitcnt vmcnt(0)" ::: "memory");
    BAR();

    // ---- ph3: stage B(kt+2)h1; MFMA rows 6-7; then read next tile's bfr+af0 ----
    if (stg) STAGE_B(1, kc);
    BAR();
    __builtin_amdgcn_s_setprio(1);
#pragma unroll
    for (int m2 = 0; m2 < 2; ++m2)
#pragma unroll
      for (int ni = 0; ni < 4; ++ni)
#pragma unroll
        for (int kk = 0; kk < 2; ++kk)
          acc[6 + m2][ni] = __builtin_amdgcn_mfma_f32_16x16x32_bf16(af3[m2][kk], bfr[ni][kk],
                                                                    acc[6 + m2][ni], 0, 0, 0);
    __builtin_amdgcn_s_setprio(0);
    if (nxt) {
      const ushort* aN0 = pA1 + laneAOff + xo0;
      const ushort* aN1 = pA1 + laneAOff + xo1;
      const ushort* bN0 = pB1 + laneBOff + xo0;
      const ushort* bN1 = pB1 + laneBOff + xo1;
#pragma unroll
      for (int ni = 0; ni < 4; ++ni) {
        bfr[ni][0] = *(const bf16x8*)(bN0 + ni * 1024);
        bfr[ni][1] = *(const bf16x8*)(bN1 + ni * 1024);
      }
#pragma unroll
      for (int m2 = 0; m2 < 2; ++m2) {
        af0[m2][0] = *(const bf16x8*)(aN0 + m2 * 1024);
        af0[m2][1] = *(const bf16x8*)(aN1 + m2 * 1024);
      }
    }
    BAR();

    // rotate slots: A three-way, B swap
    { ushort* t = pA0; pA0 = pA1; pA1 = pA2; pA2 = t; }
    { ushort* t = pB0; pB0 = pB1; pB1 = t; }
  }

  const float alpha = scalep[0] * wscale2p[0];
#pragma unroll
  for (int mi = 0; mi < 8; ++mi)
#pragma unroll
    for (int ni = 0; ni < 4; ++ni) {
      const int col = n0 + wn * 64 + ni * 16 + fr;
      const int rbase = m0 + wm * 128 + mi * 16 + fq * 4;
#pragma unroll
      for (int r = 0; r < 4; ++r)
        C[(size_t)(rbase + r) * Ndim + col] = alpha * acc[mi][ni][r];
    }
}

// ---------------- launcher ----------------

extern "C" void kernel_launch(void* const* d_in, const int* in_sizes, int n_in,
                              void* d_out, int out_size, void* d_ws, size_t ws_size,
                              hipStream_t stream) {
  const float* x       = (const float*)d_in[0];
  const int*   w       = (const int*)d_in[1];
  const float* wscale  = (const float*)d_in[2];
  const float* wscale2 = (const float*)d_in[3];
  const float* scale   = (const float*)d_in[4];
  float* out = (float*)d_out;

  ushort* a_deq = (ushort*)d_ws;                       // 32 MB
  ushort* b_deq = a_deq + (size_t)Mdim * Kdim;         // 32 MB

  silu_quant_kernel<<<Mdim, 256, 0, stream>>>(x, a_deq, scale);
  wdeq_kernel<<<Ndim, 256, 0, stream>>>(w, wscale, b_deq);

  hipFuncSetAttribute((const void*)gemm256, hipFuncAttributeMaxDynamicSharedMemorySize, 163840);
  gemm256<<<(Mdim / BM) * (Ndim / BN), 512, 163840, stream>>>(a_deq, b_deq, out, scale, wscale2);
}